// Round 11
// baseline (854.820 us; speedup 1.0000x reference)
//
#include <hip/hip_runtime.h>
#include <hip/hip_bf16.h>
#include <stdint.h>

// Problem constants (from reference)
#define IN_F 4096
#define OUT_F 11008
#define M_ROWS 8192              // 4 * 2048
#define NIG 512                  // IN_FEATURES / IN_GROUP(8)
#define CBSZ 256

typedef _Float16 f16x8 __attribute__((ext_vector_type(8)));
typedef float f32x4 __attribute__((ext_vector_type(4)));

// ---------------------------------------------------------------------------
// Kernel 1: dequantize W (UNSCALED: scales applied in GEMM epilogue in fp32).
// ---------------------------------------------------------------------------
__global__ __launch_bounds__(256) void dequant_w_kernel(
    const int* __restrict__ codes, const float* __restrict__ cbs,
    _Float16* __restrict__ W)
{
  const int idx = blockIdx.x * 256 + threadIdx.x;   // o*512 + g (exact grid)
  const int2 c = ((const int2*)codes)[idx];
  const float4* e0 = (const float4*)(cbs + (size_t)c.x * 8);
  const float4* e1 = (const float4*)(cbs + (size_t)CBSZ * 8 + (size_t)c.y * 8);
  const float4 a0 = e0[0], a1 = e0[1];
  const float4 b0 = e1[0], b1 = e1[1];
  f16x8 w;
  w[0] = (_Float16)(a0.x + b0.x);
  w[1] = (_Float16)(a0.y + b0.y);
  w[2] = (_Float16)(a0.z + b0.z);
  w[3] = (_Float16)(a0.w + b0.w);
  w[4] = (_Float16)(a1.x + b1.x);
  w[5] = (_Float16)(a1.y + b1.y);
  w[6] = (_Float16)(a1.z + b1.z);
  w[7] = (_Float16)(a1.w + b1.w);
  *(f16x8*)(W + (size_t)idx * 8) = w;
}

// ---------------------------------------------------------------------------
// Kernel 2: x fp32 -> f16, 8 elems/thread, vectorized.
// ---------------------------------------------------------------------------
__global__ __launch_bounds__(256) void convert_x_kernel(
    const float* __restrict__ x, _Float16* __restrict__ X)
{
  const size_t i = ((size_t)blockIdx.x * 256 + threadIdx.x) * 8;
  const float4 a = *(const float4*)(x + i);
  const float4 b = *(const float4*)(x + i + 4);
  f16x8 v;
  v[0] = (_Float16)a.x; v[1] = (_Float16)a.y;
  v[2] = (_Float16)a.z; v[3] = (_Float16)a.w;
  v[4] = (_Float16)b.x; v[5] = (_Float16)b.y;
  v[6] = (_Float16)b.z; v[7] = (_Float16)b.w;
  *(f16x8*)(X + i) = v;
}

// ---------------------------------------------------------------------------
// Kernel 3: 256x256x64 f16 GEMM — ONE-BARRIER-PER-TILE free-flow schedule.
//
// WHY (r6/r9/r10 post-mortem): three different phase-split schedules all
// plateau at MfmaUtil 44-45% with 0 bank conflicts and no spill. Cycle books
// (per-SIMD): MFMA 128 inst x 19.4cy = 2480cy/tile; LDS reads 192 b128 =
// 1500-2300cy; measured 5440cy/tile => LDS and MFMA are SERIALIZED by the
// 4-8 s_barriers/tile that re-lockstep all 8 waves every few hundred cycles.
// Fix: exactly ONE s_barrier per K-tile. Reads flow into MFMA with no sync
// (compiler emits fine-grained counted lgkmcnt — m97-proven); waves skew up
// to a full tile, so one wave's ds_reads overlap another's MFMA cluster
// (m114 implicit overlap). sched_barrier(0) at group boundaries only, to cap
// the fragment live-set (<=48 VGPR) without forcing wave alignment.
//
// Per tile t (parity P; reads from buf[P], stages t+1 -> buf[1-P]):
//   stage all 8 calls (A02,A13,B01,B23 of t+1)   [slack ~= full tile >> HBM lat]
//   SBAR0
//   reads c0-group (al0,bl0,bh0,ah0 = 12 b128) ; SBAR0
//   PRIO1 32 MFMA (Q1..Q4, k-half 0) PRIO0 ; SBAR0
//   reads c1-group (12 b128) ; SBAR0
//   PRIO1 32 MFMA (k-half 1) PRIO0 ; SBAR0
//   vmcnt(0) ; s_barrier          // publish t+1; WAR-release buf[1-P]
// WAR: stages(t+1)->buf[1-P] issue at start of t; buf[1-P]'s readers (tile
// t-1) all completed before end-bar(t-1). RAW: reads(t) gated by end-bar(t-1)
// whose vmcnt(0) retired the t-staging. Drain cost ~0: issue-to-drain
// distance is the whole tile (~2500cy) vs ~900cy HBM latency.
//
// Geometry/swizzle/staging identical to r9/r10 (verified): 512 thr = 8 waves
// (2M x 4N), per-wave out 128x64; LDS 2 x (A|B)[256][64] f16 = 128 KB;
// swizzle chunk_lds = chunk ^ (row&7) (0 conflicts measured); staging
// pre-permutes global source col, LDS dest linear.
// ---------------------------------------------------------------------------
#define BM 256
#define BN 256
#define BK 64
#define NKT (IN_F / BK)          // 64
#define GRID_MT (M_ROWS / BM)    // 32
#define GRID_NT (OUT_F / BN)     // 43

__global__ __launch_bounds__(512, 2) void gemm_pipe(
    const _Float16* __restrict__ X, const _Float16* __restrict__ Wd,
    const float* __restrict__ scales, const float* __restrict__ bias,
    float* __restrict__ out)
{
  __shared__ char smem[131072];  // [2 bufs][A 32KB | B 32KB]

  // T1: XCD swizzle; nwg = 1376 % 8 == 0 -> simple form bijective
  const int cpx = (GRID_MT * GRID_NT) >> 3;        // 172
  const int wg = (blockIdx.x & 7) * cpx + (blockIdx.x >> 3);
  const int mt = wg & (GRID_MT - 1), nt = wg >> 5; // m-inner: same B-panel per XCD
  const int m0 = mt * BM, n0 = nt * BN;

  const int t_ = threadIdx.x;
  const int wave = t_ >> 6, lane = t_ & 63;
  const int wm = wave >> 2, wn = wave & 3;
  const int r16 = lane & 15;
  const int q = lane >> 4;                         // 16B piece within 64B k-half
  const int sw = r16 & 7;                          // row&7 (rows offset by mult of 16)
  const int c0 = ((q ^ sw) << 4);                  // swizzled chunk byte, k-half 0
  const int c1 = (((4 | q) ^ sw) << 4);            // swizzled chunk byte, k-half 1

  // Staging: thread t's 16B lands at linear LDS byte (call*8192 + t*16)
  //   -> row = call*64 + (t>>3), chunk_lds = t&7; logical chunk = (t&7)^((t>>3)&7)
  const int s_row0 = t_ >> 3;
  const int s_col  = (((t_ & 7) ^ ((t_ >> 3) & 7)) << 3);
  const _Float16* asrc = X  + (size_t)(m0 + s_row0) * IN_F + s_col;
  const _Float16* bsrc = Wd + (size_t)(n0 + s_row0) * IN_F + s_col;
  const int s_dst = wave * 1024;                   // wave-uniform; HW adds lane*16

  f32x4 acc[8][4] = {};
  // Within-tile fragments only (no cross-tile carry). Live-set capped by
  // sched_barrier group fences at ~12 frags (48 VGPR).
  f16x8 al0[4], al1[4], ah0[4], ah1[4], bl0[2], bl1[2], bh0[2], bh1[2];

#define GLD(gsrc, ldst) __builtin_amdgcn_global_load_lds(                     \
    (const __attribute__((address_space(1))) void*)(gsrc),                    \
    (__attribute__((address_space(3))) void*)(ldst), 16, 0, 0)
#define STAGE_A(kt, bufc, i) GLD(asrc + (size_t)(kt) * BK + (size_t)(i) * 64 * IN_F, \
    smem + (bufc) * 65536 + (i) * 8192 + s_dst)
#define STAGE_B(kt, bufc, i) GLD(bsrc + (size_t)(kt) * BK + (size_t)(i) * 64 * IN_F, \
    smem + (bufc) * 65536 + 32768 + (i) * 8192 + s_dst)

#define RD_A(bufp, mm, cc) (*(const f16x8*)((bufp) + ((wm * 128 + (mm) * 16 + r16) << 7) + (cc)))
#define RD_B(bufp, nn, cc) (*(const f16x8*)((bufp) + 32768 + ((wn * 64 + (nn) * 16 + r16) << 7) + (cc)))

#define BAR   __builtin_amdgcn_s_barrier()
#define PRIO1 __builtin_amdgcn_s_setprio(1)
#define PRIO0 __builtin_amdgcn_s_setprio(0)
#define SBAR0 __builtin_amdgcn_sched_barrier(0)
#define VM0 asm volatile("s_waitcnt vmcnt(0)" ::: "memory")

// 8-MFMA group: 4 m-frags x 2 n-frags into acc[MO..][NO..]
#define MG(AF, BF, MO, NO)                                                    \
    _Pragma("unroll")                                                         \
    for (int m = 0; m < 4; ++m)                                               \
      _Pragma("unroll")                                                       \
      for (int n = 0; n < 2; ++n)                                             \
        acc[(MO) + m][(NO) + n] = __builtin_amdgcn_mfma_f32_16x16x32_f16(     \
            AF[m], BF[n], acc[(MO) + m][(NO) + n], 0, 0, 0)

// One K-tile, free-flow, ONE s_barrier. P: parity. STG: stage t+1. GATE: 1
// for vmcnt(0)+BAR publish (all tiles except the last).
#define TILE(P, tt, STG, GATE) do {                                           \
    const char* bufT = smem + (P) * 65536;                                    \
    if (STG) {                                                                \
      STAGE_A((tt) + 1, 1 - (P), 0); STAGE_A((tt) + 1, 1 - (P), 1);           \
      STAGE_A((tt) + 1, 1 - (P), 2); STAGE_A((tt) + 1, 1 - (P), 3);           \
      STAGE_B((tt) + 1, 1 - (P), 0); STAGE_B((tt) + 1, 1 - (P), 1);           \
      STAGE_B((tt) + 1, 1 - (P), 2); STAGE_B((tt) + 1, 1 - (P), 3);           \
    }                                                                         \
    SBAR0;                                                                    \
    /* ---- k-half 0: reads flow into MFMA (no barrier; compiler lgkm) */     \
    _Pragma("unroll")                                                         \
    for (int m = 0; m < 4; ++m) al0[m] = RD_A(bufT, m, c0);                   \
    _Pragma("unroll")                                                         \
    for (int n = 0; n < 2; ++n) { bl0[n] = RD_B(bufT, n, c0);                 \
                                  bh0[n] = RD_B(bufT, 2 + n, c0); }           \
    _Pragma("unroll")                                                         \
    for (int m = 0; m < 4; ++m) ah0[m] = RD_A(bufT, 4 + m, c0);               \
    SBAR0;                                                                    \
    PRIO1;                                                                    \
    MG(al0, bl0, 0, 0); MG(al0, bh0, 0, 2);                                   \
    MG(ah0, bh0, 4, 2); MG(ah0, bl0, 4, 0);                                   \
    PRIO0;                                                                    \
    SBAR0;                                                                    \
    /* ---- k-half 1 */                                                       \
    _Pragma("unroll")                                                         \
    for (int m = 0; m < 4; ++m) al1[m] = RD_A(bufT, m, c1);                   \
    _Pragma("unroll")                                                         \
    for (int n = 0; n < 2; ++n) { bl1[n] = RD_B(bufT, n, c1);                 \
                                  bh1[n] = RD_B(bufT, 2 + n, c1); }           \
    _Pragma("unroll")                                                         \
    for (int m = 0; m < 4; ++m) ah1[m] = RD_A(bufT, 4 + m, c1);               \
    SBAR0;                                                                    \
    PRIO1;                                                                    \
    MG(al1, bl1, 0, 0); MG(al1, bh1, 0, 2);                                   \
    MG(ah1, bh1, 4, 2); MG(ah1, bl1, 4, 0);                                   \
    PRIO0;                                                                    \
    SBAR0;                                                                    \
    if (GATE) { VM0; BAR; }   /* publish tile t+1; WAR-release buf[1-P] */    \
  } while (0)

  // ---- Prologue: stage tile 0 into buf0, drain, publish
  STAGE_A(0, 0, 0); STAGE_A(0, 0, 1); STAGE_A(0, 0, 2); STAGE_A(0, 0, 3);
  STAGE_B(0, 0, 0); STAGE_B(0, 0, 1); STAGE_B(0, 0, 2); STAGE_B(0, 0, 3);
  VM0;
  BAR;

  // ---- Main loop: tiles 0..62 stage next tile; tile 63 is bare
  #pragma unroll 1
  for (int t = 0; t < 62; t += 2) {
    TILE(0, t,     1, 1);
    TILE(1, t + 1, 1, 1);
  }
  TILE(0, 62, 1, 1);
  TILE(1, 63, 0, 0);

  // Epilogue: acc * scales[col] + bias[col], fp32.
  // C/D frag: col = lane&15, row = (lane>>4)*4 + reg (m89-verified).
  const int crow = (lane >> 4) << 2;
  #pragma unroll
  for (int nf = 0; nf < 4; ++nf) {
    const int col = n0 + wn * 64 + nf * 16 + r16;
    const float s = scales[col];
    const float bb = bias[col];
    #pragma unroll
    for (int mf = 0; mf < 8; ++mf) {
      const int rb = m0 + wm * 128 + mf * 16 + crow;
      #pragma unroll
      for (int r = 0; r < 4; ++r)
        out[(size_t)(rb + r) * OUT_F + col] = acc[mf][nf][r] * s + bb;
    }
  }
#undef TILE
#undef MG
#undef RD_A
#undef RD_B
#undef STAGE_A
#undef STAGE_B
#undef GLD
}

// ---------------------------------------------------------------------------
// Fallback (only if ws too small): correct but slow fp32 path.
// ---------------------------------------------------------------------------
__global__ __launch_bounds__(256) void naive_kernel(
    const float* __restrict__ x, const int* __restrict__ codes,
    const float* __restrict__ cbs, const float* __restrict__ scales,
    const float* __restrict__ bias, float* __restrict__ out)
{
  __shared__ float xrow[IN_F];
  const int m = blockIdx.x;
  for (int i = threadIdx.x; i < IN_F; i += 256)
    xrow[i] = x[(size_t)m * IN_F + i];
  __syncthreads();
  for (int o = threadIdx.x; o < OUT_F; o += 256) {
    float acc = 0.f;
    const int2* crow = (const int2*)codes + (size_t)o * NIG;
    for (int g = 0; g < NIG; ++g) {
      const int2 c = crow[g];
      const float* e0 = cbs + (size_t)c.x * 8;
      const float* e1 = cbs + (size_t)CBSZ * 8 + (size_t)c.y * 8;
      const float* xr = xrow + g * 8;
      #pragma unroll
      for (int j = 0; j < 8; ++j) acc += (e0[j] + e1[j]) * xr[j];
    }
    out[(size_t)m * OUT_F + o] = acc * scales[o] + bias[o];
  }
}

// ---------------------------------------------------------------------------
extern "C" void kernel_launch(void* const* d_in, const int* in_sizes, int n_in,
                              void* d_out, int out_size, void* d_ws, size_t ws_size,
                              hipStream_t stream) {
  const float* x      = (const float*)d_in[0];
  const int*   codes  = (const int*)d_in[1];
  const float* cbs    = (const float*)d_in[2];
  const float* scales = (const float*)d_in[3];
  const float* bias   = (const float*)d_in[4];
  float* out = (float*)d_out;

  const size_t W_BYTES = (size_t)OUT_F * IN_F * sizeof(_Float16);  // 90.2 MB
  const size_t X_BYTES = (size_t)M_ROWS * IN_F * sizeof(_Float16); // 67.1 MB

  if (ws_size < W_BYTES + X_BYTES) {
    naive_kernel<<<M_ROWS, 256, 0, stream>>>(x, codes, cbs, scales, bias, out);
    return;
  }

  _Float16* W = (_Float16*)d_ws;
  _Float16* X = (_Float16*)((char*)d_ws + W_BYTES);

  dequant_w_kernel<<<(OUT_F * NIG) / 256, 256, 0, stream>>>(codes, cbs, W);
  convert_x_kernel<<<(M_ROWS * IN_F / 8) / 256, 256, 0, stream>>>(x, X);
  gemm_pipe<<<GRID_MT * GRID_NT, 512, 0, stream>>>(X, W, scales, bias, out);
}

// Round 12
// 853.453 us; speedup vs baseline: 1.0016x; 1.0016x over previous
//
#include <hip/hip_runtime.h>
#include <hip/hip_bf16.h>
#include <stdint.h>

// Problem constants (from reference)
#define IN_F 4096
#define OUT_F 11008
#define M_ROWS 8192              // 4 * 2048
#define NIG 512                  // IN_FEATURES / IN_GROUP(8)
#define CBSZ 256

typedef _Float16 f16x8 __attribute__((ext_vector_type(8)));
typedef float f32x4 __attribute__((ext_vector_type(4)));

// ---------------------------------------------------------------------------
// Kernel 1: dequantize W (UNSCALED: scales applied in GEMM epilogue in fp32).
// ---------------------------------------------------------------------------
__global__ __launch_bounds__(256) void dequant_w_kernel(
    const int* __restrict__ codes, const float* __restrict__ cbs,
    _Float16* __restrict__ W)
{
  const int idx = blockIdx.x * 256 + threadIdx.x;   // o*512 + g (exact grid)
  const int2 c = ((const int2*)codes)[idx];
  const float4* e0 = (const float4*)(cbs + (size_t)c.x * 8);
  const float4* e1 = (const float4*)(cbs + (size_t)CBSZ * 8 + (size_t)c.y * 8);
  const float4 a0 = e0[0], a1 = e0[1];
  const float4 b0 = e1[0], b1 = e1[1];
  f16x8 w;
  w[0] = (_Float16)(a0.x + b0.x);
  w[1] = (_Float16)(a0.y + b0.y);
  w[2] = (_Float16)(a0.z + b0.z);
  w[3] = (_Float16)(a0.w + b0.w);
  w[4] = (_Float16)(a1.x + b1.x);
  w[5] = (_Float16)(a1.y + b1.y);
  w[6] = (_Float16)(a1.z + b1.z);
  w[7] = (_Float16)(a1.w + b1.w);
  *(f16x8*)(W + (size_t)idx * 8) = w;
}

// ---------------------------------------------------------------------------
// Kernel 2: x fp32 -> f16, 8 elems/thread, vectorized.
// ---------------------------------------------------------------------------
__global__ __launch_bounds__(256) void convert_x_kernel(
    const float* __restrict__ x, _Float16* __restrict__ X)
{
  const size_t i = ((size_t)blockIdx.x * 256 + threadIdx.x) * 8;
  const float4 a = *(const float4*)(x + i);
  const float4 b = *(const float4*)(x + i + 4);
  f16x8 v;
  v[0] = (_Float16)a.x; v[1] = (_Float16)a.y;
  v[2] = (_Float16)a.z; v[3] = (_Float16)a.w;
  v[4] = (_Float16)b.x; v[5] = (_Float16)b.y;
  v[6] = (_Float16)b.z; v[7] = (_Float16)b.w;
  *(f16x8*)(X + i) = v;
}

// ---------------------------------------------------------------------------
// Kernel 3: 256x256x64 f16 GEMM — one barrier/tile + ANTI-PHASED WAVE PAIRS.
//
// WHY (r6..r11 post-mortem): four different schedules all plateau at MfmaUtil
// 42-46%. Cycle books per CU per tile: MFMA-pipe 2480cy, LDS-port 2800cy
// (192 b128 reads + 64KB staged writes); measured 5440cy = 2480+2800 =
// FULLY SERIALIZED in every schedule, though they are different pipes.
// Convoy effect: both waves of a SIMD run the same program from the same
// barrier -> both burst ds_reads together (shared LDS queue serializes all),
// both wait, both MFMA. Wave-level overlap (m114) needs waves in DIFFERENT
// phases; nothing ever breaks the symmetry.
//
// FIX: same-SIMD pairs are (w, w+4) -> parity bit = wm. Waves wm=0 process
// k-half 0 then 1; wm=1 process k-half 1 then 0. Implemented by per-wave
// byte offsets cA/cB (code path identical, wave-uniform, no divergence).
// At any instant ~half the waves read LDS while the other half run MFMA.
// Accumulation order across k-halves is a reorder only (same acc targets).
//
// Geometry/swizzle/staging identical to r9..r11 (verified): 512 thr = 8 waves
// (2M x 4N), per-wave out 128x64; LDS 2 x (A|B)[256][64] f16 = 128 KB;
// swizzle chunk_lds = chunk ^ (row&7) (0 conflicts measured); staging
// pre-permutes global source col, LDS dest linear. One vmcnt(0)+barrier per
// tile publishes t+1 and WAR-releases buf[1-P] (issue-to-drain ~ full tile
// >> 900cy HBM latency).
// ---------------------------------------------------------------------------
#define BM 256
#define BN 256
#define BK 64
#define NKT (IN_F / BK)          // 64
#define GRID_MT (M_ROWS / BM)    // 32
#define GRID_NT (OUT_F / BN)     // 43

__global__ __launch_bounds__(512, 2) void gemm_pipe(
    const _Float16* __restrict__ X, const _Float16* __restrict__ Wd,
    const float* __restrict__ scales, const float* __restrict__ bias,
    float* __restrict__ out)
{
  __shared__ char smem[131072];  // [2 bufs][A 32KB | B 32KB]

  // T1: XCD swizzle; nwg = 1376 % 8 == 0 -> simple form bijective
  const int cpx = (GRID_MT * GRID_NT) >> 3;        // 172
  const int wg = (blockIdx.x & 7) * cpx + (blockIdx.x >> 3);
  const int mt = wg & (GRID_MT - 1), nt = wg >> 5; // m-inner: same B-panel per XCD
  const int m0 = mt * BM, n0 = nt * BN;

  const int t_ = threadIdx.x;
  const int wave = t_ >> 6, lane = t_ & 63;
  const int wm = wave >> 2, wn = wave & 3;
  const int r16 = lane & 15;
  const int q = lane >> 4;                         // 16B piece within 64B k-half
  const int sw = r16 & 7;                          // row&7 (rows offset by mult of 16)
  const int c0 = ((q ^ sw) << 4);                  // swizzled chunk byte, k-half 0
  const int c1 = (((4 | q) ^ sw) << 4);            // swizzled chunk byte, k-half 1
  // ANTI-PHASE: same-SIMD wave pairs are (w, w+4) -> parity = wm.
  // wm=0 waves consume k-half 0 first; wm=1 waves k-half 1 first.
  const int cA = wm ? c1 : c0;                     // this wave's FIRST k-half
  const int cB = wm ? c0 : c1;                     // this wave's SECOND k-half

  // Staging: thread t's 16B lands at linear LDS byte (call*8192 + t*16)
  //   -> row = call*64 + (t>>3), chunk_lds = t&7; logical chunk = (t&7)^((t>>3)&7)
  const int s_row0 = t_ >> 3;
  const int s_col  = (((t_ & 7) ^ ((t_ >> 3) & 7)) << 3);
  const _Float16* asrc = X  + (size_t)(m0 + s_row0) * IN_F + s_col;
  const _Float16* bsrc = Wd + (size_t)(n0 + s_row0) * IN_F + s_col;
  const int s_dst = wave * 1024;                   // wave-uniform; HW adds lane*16

  f32x4 acc[8][4] = {};
  // Within-tile fragments only (no cross-tile carry); "0" = first k-half (cA),
  // "1" = second k-half (cB) — wave-relative, both A and B consistent.
  f16x8 al0[4], al1[4], ah0[4], ah1[4], bl0[2], bl1[2], bh0[2], bh1[2];

#define GLD(gsrc, ldst) __builtin_amdgcn_global_load_lds(                     \
    (const __attribute__((address_space(1))) void*)(gsrc),                    \
    (__attribute__((address_space(3))) void*)(ldst), 16, 0, 0)
#define STAGE_A(kt, bufc, i) GLD(asrc + (size_t)(kt) * BK + (size_t)(i) * 64 * IN_F, \
    smem + (bufc) * 65536 + (i) * 8192 + s_dst)
#define STAGE_B(kt, bufc, i) GLD(bsrc + (size_t)(kt) * BK + (size_t)(i) * 64 * IN_F, \
    smem + (bufc) * 65536 + 32768 + (i) * 8192 + s_dst)

#define RD_A(bufp, mm, cc) (*(const f16x8*)((bufp) + ((wm * 128 + (mm) * 16 + r16) << 7) + (cc)))
#define RD_B(bufp, nn, cc) (*(const f16x8*)((bufp) + 32768 + ((wn * 64 + (nn) * 16 + r16) << 7) + (cc)))

#define BAR   __builtin_amdgcn_s_barrier()
#define PRIO1 __builtin_amdgcn_s_setprio(1)
#define PRIO0 __builtin_amdgcn_s_setprio(0)
#define SBAR0 __builtin_amdgcn_sched_barrier(0)
#define VM0 asm volatile("s_waitcnt vmcnt(0)" ::: "memory")

// 8-MFMA group: 4 m-frags x 2 n-frags into acc[MO..][NO..]
#define MG(AF, BF, MO, NO)                                                    \
    _Pragma("unroll")                                                         \
    for (int m = 0; m < 4; ++m)                                               \
      _Pragma("unroll")                                                       \
      for (int n = 0; n < 2; ++n)                                             \
        acc[(MO) + m][(NO) + n] = __builtin_amdgcn_mfma_f32_16x16x32_f16(     \
            AF[m], BF[n], acc[(MO) + m][(NO) + n], 0, 0, 0)

// One K-tile, free-flow, ONE s_barrier, anti-phased k-half order via cA/cB.
// P: parity. STG: stage t+1. GATE: 1 for vmcnt(0)+BAR publish.
#define TILE(P, tt, STG, GATE) do {                                           \
    const char* bufT = smem + (P) * 65536;                                    \
    if (STG) {                                                                \
      STAGE_A((tt) + 1, 1 - (P), 0); STAGE_A((tt) + 1, 1 - (P), 1);           \
      STAGE_A((tt) + 1, 1 - (P), 2); STAGE_A((tt) + 1, 1 - (P), 3);           \
      STAGE_B((tt) + 1, 1 - (P), 0); STAGE_B((tt) + 1, 1 - (P), 1);           \
      STAGE_B((tt) + 1, 1 - (P), 2); STAGE_B((tt) + 1, 1 - (P), 3);           \
    }                                                                         \
    SBAR0;                                                                    \
    /* ---- FIRST k-half (cA): reads flow into MFMA (compiler lgkm) */        \
    _Pragma("unroll")                                                         \
    for (int m = 0; m < 4; ++m) al0[m] = RD_A(bufT, m, cA);                   \
    _Pragma("unroll")                                                         \
    for (int n = 0; n < 2; ++n) { bl0[n] = RD_B(bufT, n, cA);                 \
                                  bh0[n] = RD_B(bufT, 2 + n, cA); }           \
    _Pragma("unroll")                                                         \
    for (int m = 0; m < 4; ++m) ah0[m] = RD_A(bufT, 4 + m, cA);               \
    SBAR0;                                                                    \
    PRIO1;                                                                    \
    MG(al0, bl0, 0, 0); MG(al0, bh0, 0, 2);                                   \
    MG(ah0, bh0, 4, 2); MG(ah0, bl0, 4, 0);                                   \
    PRIO0;                                                                    \
    SBAR0;                                                                    \
    /* ---- SECOND k-half (cB) */                                             \
    _Pragma("unroll")                                                         \
    for (int m = 0; m < 4; ++m) al1[m] = RD_A(bufT, m, cB);                   \
    _Pragma("unroll")                                                         \
    for (int n = 0; n < 2; ++n) { bl1[n] = RD_B(bufT, n, cB);                 \
                                  bh1[n] = RD_B(bufT, 2 + n, cB); }           \
    _Pragma("unroll")                                                         \
    for (int m = 0; m < 4; ++m) ah1[m] = RD_A(bufT, 4 + m, cB);               \
    SBAR0;                                                                    \
    PRIO1;                                                                    \
    MG(al1, bl1, 0, 0); MG(al1, bh1, 0, 2);                                   \
    MG(ah1, bh1, 4, 2); MG(ah1, bl1, 4, 0);                                   \
    PRIO0;                                                                    \
    SBAR0;                                                                    \
    if (GATE) { VM0; BAR; }   /* publish tile t+1; WAR-release buf[1-P] */    \
  } while (0)

  // ---- Prologue: stage tile 0 into buf0, drain, publish
  STAGE_A(0, 0, 0); STAGE_A(0, 0, 1); STAGE_A(0, 0, 2); STAGE_A(0, 0, 3);
  STAGE_B(0, 0, 0); STAGE_B(0, 0, 1); STAGE_B(0, 0, 2); STAGE_B(0, 0, 3);
  VM0;
  BAR;

  // ---- Main loop: tiles 0..62 stage next tile; tile 63 is bare
  #pragma unroll 1
  for (int t = 0; t < 62; t += 2) {
    TILE(0, t,     1, 1);
    TILE(1, t + 1, 1, 1);
  }
  TILE(0, 62, 1, 1);
  TILE(1, 63, 0, 0);

  // Epilogue: acc * scales[col] + bias[col], fp32.
  // C/D frag: col = lane&15, row = (lane>>4)*4 + reg (m89-verified).
  const int crow = (lane >> 4) << 2;
  #pragma unroll
  for (int nf = 0; nf < 4; ++nf) {
    const int col = n0 + wn * 64 + nf * 16 + r16;
    const float s = scales[col];
    const float bb = bias[col];
    #pragma unroll
    for (int mf = 0; mf < 8; ++mf) {
      const int rb = m0 + wm * 128 + mf * 16 + crow;
      #pragma unroll
      for (int r = 0; r < 4; ++r)
        out[(size_t)(rb + r) * OUT_F + col] = acc[mf][nf][r] * s + bb;
    }
  }
#undef TILE
#undef MG
#undef RD_A
#undef RD_B
#undef STAGE_A
#undef STAGE_B
#undef GLD
}

// ---------------------------------------------------------------------------
// Fallback (only if ws too small): correct but slow fp32 path.
// ---------------------------------------------------------------------------
__global__ __launch_bounds__(256) void naive_kernel(
    const float* __restrict__ x, const int* __restrict__ codes,
    const float* __restrict__ cbs, const float* __restrict__ scales,
    const float* __restrict__ bias, float* __restrict__ out)
{
  __shared__ float xrow[IN_F];
  const int m = blockIdx.x;
  for (int i = threadIdx.x; i < IN_F; i += 256)
    xrow[i] = x[(size_t)m * IN_F + i];
  __syncthreads();
  for (int o = threadIdx.x; o < OUT_F; o += 256) {
    float acc = 0.f;
    const int2* crow = (const int2*)codes + (size_t)o * NIG;
    for (int g = 0; g < NIG; ++g) {
      const int2 c = crow[g];
      const float* e0 = cbs + (size_t)c.x * 8;
      const float* e1 = cbs + (size_t)CBSZ * 8 + (size_t)c.y * 8;
      const float* xr = xrow + g * 8;
      #pragma unroll
      for (int j = 0; j < 8; ++j) acc += (e0[j] + e1[j]) * xr[j];
    }
    out[(size_t)m * OUT_F + o] = acc * scales[o] + bias[o];
  }
}

// ---------------------------------------------------------------------------
extern "C" void kernel_launch(void* const* d_in, const int* in_sizes, int n_in,
                              void* d_out, int out_size, void* d_ws, size_t ws_size,
                              hipStream_t stream) {
  const float* x      = (const float*)d_in[0];
  const int*   codes  = (const int*)d_in[1];
  const float* cbs    = (const float*)d_in[2];
  const float* scales = (const float*)d_in[3];
  const float* bias   = (const float*)d_in[4];
  float* out = (float*)d_out;

  const size_t W_BYTES = (size_t)OUT_F * IN_F * sizeof(_Float16);  // 90.2 MB
  const size_t X_BYTES = (size_t)M_ROWS * IN_F * sizeof(_Float16); // 67.1 MB

  if (ws_size < W_BYTES + X_BYTES) {
    naive_kernel<<<M_ROWS, 256, 0, stream>>>(x, codes, cbs, scales, bias, out);
    return;
  }

  _Float16* W = (_Float16*)d_ws;
  _Float16* X = (_Float16*)((char*)d_ws + W_BYTES);

  dequant_w_kernel<<<(OUT_F * NIG) / 256, 256, 0, stream>>>(codes, cbs, W);
  convert_x_kernel<<<(M_ROWS * IN_F / 8) / 256, 256, 0, stream>>>(x, X);
  gemm_pipe<<<GRID_MT * GRID_NT, 512, 0, stream>>>(X, W, scales, bias, out);
}